// Round 15
// baseline (178.453 us; speedup 1.0000x reference)
//
#include <hip/hip_runtime.h>

// VMD (Variational Mode Decomposition) for x: (16, 8192, 4) f32.
// B=16, C=4, T=8192, T2=16384, K=4, ALPHA=2000, TAU=0, 20 iterations.
// TAU=0 => lam == 0. Negative half stays 0 => iterate on 8192 positive bins.
//
// R15 = R14 + v_fma_mix_f32 in the iteration inner loop: the f16-U
// unpack(2x v_cvt_f32_f16)+v_pk_add_f32 (3 instr per u,k) becomes
// 2x v_fma_mix_f32 (f16-half source, +1.0, f32 acc) -> saves 32 instr/iter
// (~7% of the issue-bound iteration body). Bench accounting across
// R11/R13/R14 shows ~45-50us fixed harness overhead + inverse ~10-15us;
// the controllable cost is the forward kernel (FFT ~30us + iteration ~70us).

#define HALF      8192
#define NH        8192        // half-size FFT length
#define NTHREADS  1024
#define KMODES    4
#define NITERS    20
#define ALPHA_F   2000.0f
#define SQH       0.70710678118654752440f

typedef __fp16 half2_t __attribute__((ext_vector_type(2)));
typedef float  v2f     __attribute__((ext_vector_type(2)));

__device__ __forceinline__ unsigned bitrev13(unsigned x) { return __brev(x) >> 19; }
__device__ __forceinline__ int pidx(int i) { return i + (i >> 4); }   // LDS pad

__device__ __forceinline__ unsigned pack_h2(float a, float b) {
    half2_t h = __builtin_amdgcn_cvt_pkrtz(a, b);   // v_cvt_pkrtz_f16_f32
    return __builtin_bit_cast(unsigned, h);
}
__device__ __forceinline__ v2f unpack_h2(unsigned u) {
    half2_t h = __builtin_bit_cast(half2_t, u);
    v2f r; r.x = (float)h.x; r.y = (float)h.y; return r;
}

// f32 result = (f16 half of h2) * 1.0 + add   (one v_fma_mix_f32)
__device__ __forceinline__ float fma_mix_lo(unsigned h2, float add) {
    float r;
    asm("v_fma_mix_f32 %0, %1, 1.0, %2 op_sel:[0,0,0] op_sel_hi:[1,0,0]"
        : "=v"(r) : "v"(h2), "v"(add));
    return r;
}
__device__ __forceinline__ float fma_mix_hi(unsigned h2, float add) {
    float r;
    asm("v_fma_mix_f32 %0, %1, 1.0, %2 op_sel:[1,0,0] op_sel_hi:[1,0,0]"
        : "=v"(r) : "v"(h2), "v"(add));
    return r;
}

template <int CTRL>
__device__ __forceinline__ float dpp_add_step(float v) {
    int r = __builtin_amdgcn_update_dpp(0, __float_as_int(v), CTRL, 0xf, 0xf, true);
    return v + __int_as_float(r);
}
// Full-wave (64-lane) sum; result valid in lane 63.
__device__ __forceinline__ float wave64_sum(float v) {
    v = dpp_add_step<0x111>(v);   // row_shr:1
    v = dpp_add_step<0x112>(v);   // row_shr:2
    v = dpp_add_step<0x114>(v);   // row_shr:4
    v = dpp_add_step<0x118>(v);   // row_shr:8
    v = dpp_add_step<0x142>(v);   // row_bcast:15
    v = dpp_add_step<0x143>(v);   // row_bcast:31 -> lane63 = wave sum
    return v;
}

__device__ __forceinline__ float2 cmul(float2 a, float wr, float wi) {
    return make_float2(a.x * wr - a.y * wi, a.x * wi + a.y * wr);
}
__device__ __forceinline__ float2 cadd(float2 a, float2 b) {
    return make_float2(a.x + b.x, a.y + b.y);
}
__device__ __forceinline__ float2 csub(float2 a, float2 b) {
    return make_float2(a.x - b.x, a.y - b.y);
}

// One radix-8 pass = three fused radix-2 DIF stages.
template <bool INV>
__device__ __forceinline__ void fft_pass8(float2* A, int tid, int t) {
    const int   log2Q = 10 - 3 * t;
    const int   Q     = 1 << log2Q;
    const float invL  = (float)(1 << (3 * t)) * (1.0f / 8192.0f);  // 1/(8Q)
    const int j    = tid & (Q - 1);
    const int base = ((tid >> log2Q) << (log2Q + 3)) + j;

    float2 x[8];
    #pragma unroll
    for (int m = 0; m < 8; ++m) x[m] = A[pidx(base + m * Q)];

    float rev = (float)j * invL;
    float w1r = __builtin_amdgcn_cosf(rev);
    float w1i = INV ?  __builtin_amdgcn_sinf(rev)
                    : -__builtin_amdgcn_sinf(rev);
    float w2r = w1r * w1r - w1i * w1i, w2i = 2.0f * w1r * w1i;
    float w4r = w2r * w2r - w2i * w2i, w4i = 2.0f * w2r * w2i;
    float wsr, wsi;
    if (INV) { wsr = SQH * (w1r - w1i); wsi = SQH * (w1r + w1i); }
    else     { wsr = SQH * (w1r + w1i); wsi = SQH * (w1i - w1r); }
    float w1tr = INV ? -w1i : w1i,  w1ti = INV ? w1r : -w1r;
    float wstr = INV ? -wsi : wsi,  wsti = INV ? wsr : -wsr;
    float w2tr = INV ? -w2i : w2i,  w2ti = INV ? w2r : -w2r;

    float2 y0 = cadd(x[0], x[4]), y1 = cadd(x[1], x[5]);
    float2 y2 = cadd(x[2], x[6]), y3 = cadd(x[3], x[7]);
    float2 y4 = cmul(csub(x[0], x[4]), w1r, w1i);
    float2 y5 = cmul(csub(x[1], x[5]), wsr, wsi);
    float2 y6 = cmul(csub(x[2], x[6]), w1tr, w1ti);
    float2 y7 = cmul(csub(x[3], x[7]), wstr, wsti);

    float2 z0 = cadd(y0, y2), z2 = cmul(csub(y0, y2), w2r, w2i);
    float2 z1 = cadd(y1, y3), z3 = cmul(csub(y1, y3), w2tr, w2ti);
    float2 z4 = cadd(y4, y6), z6 = cmul(csub(y4, y6), w2r, w2i);
    float2 z5 = cadd(y5, y7), z7 = cmul(csub(y5, y7), w2tr, w2ti);

    A[pidx(base + 0 * Q)] = cadd(z0, z1);
    A[pidx(base + 1 * Q)] = cmul(csub(z0, z1), w4r, w4i);
    A[pidx(base + 2 * Q)] = cadd(z2, z3);
    A[pidx(base + 3 * Q)] = cmul(csub(z2, z3), w4r, w4i);
    A[pidx(base + 4 * Q)] = cadd(z4, z5);
    A[pidx(base + 5 * Q)] = cmul(csub(z4, z5), w4r, w4i);
    A[pidx(base + 6 * Q)] = cadd(z6, z7);
    A[pidx(base + 7 * Q)] = cmul(csub(z6, z7), w4r, w4i);
}

// Final radix-2 stage (half=1): pairs (2t, 2t+1), twiddle = 1.
__device__ __forceinline__ void fft_last2(float2* A, int tid) {
    #pragma unroll
    for (int u = 0; u < 4; ++u) {
        int t  = tid + u * NTHREADS;
        int i0 = 2 * t, i1 = 2 * t + 1;
        float2 a = A[pidx(i0)], b = A[pidx(i1)];
        A[pidx(i0)] = make_float2(a.x + b.x, a.y + b.y);
        A[pidx(i1)] = make_float2(a.x - b.x, a.y - b.y);
    }
}

// time-domain mirror extension: f[i], i in [0,16384)
__device__ __forceinline__ int mirror_t(int i) {
    if (i < 4096)       return 4095 - i;
    else if (i < 12288) return i - 4096;
    else                return 20479 - i;
}

// ---------------------------------------------------------------------------
// Kernel 1: per-channel real-FFT (half-size, radix-8) + 20 VMD iterations.
// One block per channel (ch = b*4 + c), 1024 threads, 8 bins/thread.
// Writes u_hat packed-f16 (unsigned per bin).
// ---------------------------------------------------------------------------
__global__ __launch_bounds__(NTHREADS) void vmd_forward_iter(
    const float* __restrict__ x, unsigned* __restrict__ ws_u,
    float* __restrict__ ws_omega)
{
    __shared__ float2 A[NH + (NH >> 4)];   // padded, ~68 KB
    const int tid = threadIdx.x;
    const int ch  = blockIdx.x;          // b*4 + c
    const int b   = ch >> 2, c = ch & 3;
    const float* xb = x + (size_t)b * 8192 * 4 + c;   // x[b, t, c], stride 4

    // z[m] = f[2m] + i f[2m+1]
    for (int m = tid; m < NH; m += NTHREADS) {
        float re = xb[(size_t)mirror_t(2 * m) * 4];
        float im = xb[(size_t)mirror_t(2 * m + 1) * 4];
        A[pidx(m)] = make_float2(re, im);
    }
    __syncthreads();

    // 8192-pt forward FFT: 4 radix-8 passes + 1 radix-2 stage; bit-reversed out.
    for (int t = 0; t < 4; ++t) {
        fft_pass8<false>(A, tid, t);
        __syncthreads();
    }
    fft_last2(A, tid);
    __syncthreads();

    // Untangle: F[j] = E[j] + w*O[j], w = e^{-2*pi*i*j/16384}, j=0..8191.
    v2f R[8];
    #pragma unroll
    for (int u = 0; u < 8; ++u) {
        int j  = tid + u * NTHREADS;
        float2 z1 = A[pidx((int)bitrev13((unsigned)j))];
        float2 z2 = A[pidx((int)bitrev13((unsigned)((NH - j) & (NH - 1))))];
        float ex = 0.5f * (z1.x + z2.x);
        float ey = 0.5f * (z1.y - z2.y);
        float dx = 0.5f * (z1.x - z2.x);
        float dy = 0.5f * (z1.y + z2.y);
        // O = (dy, -dx)
        float rev = (float)j * (1.0f / 16384.0f);
        float wr = __builtin_amdgcn_cosf(rev);
        float wi = -__builtin_amdgcn_sinf(rev);
        R[u].x = ex + wr * dy + wi * dx;
        R[u].y = ey + wi * dy - wr * dx;
    }
    __syncthreads();   // LDS now reusable as reduction scratch

    unsigned Up[KMODES][8];    // U_k packed as (f16 re, f16 im)
    #pragma unroll
    for (int u = 0; u < 8; ++u)
        #pragma unroll
        for (int k = 0; k < KMODES; ++k) Up[k][u] = 0u;

    const float f0 = (float)tid * (1.0f / 16384.0f);    // fr[u] = f0 + u/16
    float omg[KMODES] = {0.0f, 0.125f, 0.25f, 0.375f};  // 0.5*k/K

    float* red = (float*)A;   // two 136-float slabs (double-buffered by parity)
    const int lane = tid & 63, wid = tid >> 6;

    for (int it = 0; it < NITERS; ++it) {
        v2f nd[KMODES];       // (num, den) packed per mode
        #pragma unroll
        for (int k = 0; k < KMODES; ++k) { nd[k].x = 0.f; nd[k].y = 0.f; }
        #pragma unroll
        for (int u = 0; u < 8; ++u) {
            const float fru = f0 + (float)u * 0.0625f;
            v2f fv; fv.x = fru; fv.y = 1.0f;
            #pragma unroll
            for (int k = 0; k < KMODES; ++k) {
                float d   = fru - omg[k];
                float dnm = fmaf(ALPHA_F * d, d, 1.0f);
                float rcp = __builtin_amdgcn_rcpf(dnm);
                // nm = R + unpack(U)  via v_fma_mix_f32 (1 instr/component)
                v2f nm;
                nm.x = fma_mix_lo(Up[k][u], R[u].x);
                nm.y = fma_mix_hi(Up[k][u], R[u].y);
                v2f un  = nm * rcp;           // v_pk_mul_f32 (splat)
                R[u]    = nm - un;            // v_pk_add_f32
                Up[k][u] = pack_h2(un.x, un.y);
                float p = fmaf(un.x, un.x, un.y * un.y);
                nd[k]   = fv * p + nd[k];     // v_pk_fma_f32
            }
        }
        // Stage 1: DPP wave sums, lane63 writes 8 partials for this wave.
        float num[KMODES], den[KMODES];
        #pragma unroll
        for (int m = 0; m < KMODES; ++m) {
            num[m] = wave64_sum(nd[m].x);
            den[m] = wave64_sum(nd[m].y);
        }
        float* redb = red + (it & 1) * 136;
        if (lane == 63) {
            float4* r4 = (float4*)&redb[wid * 8];
            r4[0] = make_float4(num[0], num[1], num[2], num[3]);
            r4[1] = make_float4(den[0], den[1], den[2], den[3]);
        }
        __syncthreads();   // the ONLY barrier this iteration
        // Every wave redundantly folds the 16x8 partials.
        float v = redb[lane] + redb[lane + 64];
        v += __int_as_float(__builtin_amdgcn_ds_swizzle(__float_as_int(v), 0x201F)); // xor 8
        v += __int_as_float(__builtin_amdgcn_ds_swizzle(__float_as_int(v), 0x401F)); // xor 16
        v += __int_as_float(__builtin_amdgcn_ds_bpermute((lane ^ 32) << 2,
                                                         __float_as_int(v)));
        #pragma unroll
        for (int m = 0; m < KMODES; ++m) {
            float nm_ = __int_as_float(__builtin_amdgcn_readlane(__float_as_int(v), m));
            float dn_ = __int_as_float(__builtin_amdgcn_readlane(__float_as_int(v), m + 4));
            omg[m] = nm_ * __builtin_amdgcn_rcpf(dn_);
        }
    }

    // Write final positive-half u_hat (packed f16) and omega.
    #pragma unroll
    for (int k = 0; k < KMODES; ++k) {
        unsigned* dst = ws_u + (size_t)(ch * KMODES + k) * HALF;
        #pragma unroll
        for (int u = 0; u < 8; ++u)
            dst[tid + u * NTHREADS] = Up[k][u];
    }
    if (tid < KMODES) ws_omega[ch * KMODES + tid] = omg[tid];
}

// ---------------------------------------------------------------------------
// Kernel 2: per (channel,mode) half-size real iFFT -> out[b,k,t,c] scatter.
// Block remap for WRITE merging: g = bid & 63 -> (b = g>>2, k = g&3),
// c = bid >> 6, ch = b*4+c (same-XCD partial-write merging, R13).
// Block 0 also computes omega_b[b,k] = mean_c omega[b,c,k].
// Spectrum (verified R1): G[0]=conj(p[0]); G[j]=p[j]; G[8192]=conj(p[8191]);
// G[16384-j]=conj(p[j]).  Half-size: E=(G[j]+G[j+8192])/2,
// D=(G[j]-G[j+8192])/2, O=D*e^{+2pi i j/16384}, Z=E+iO, z=iFFT_8192(Z),
// x[2m]=Re z[m], x[2m+1]=Im z[m]; keep m in [2048,6144).
// ---------------------------------------------------------------------------
__global__ __launch_bounds__(NTHREADS) void vmd_inverse(
    const unsigned* __restrict__ ws_u, const float* __restrict__ ws_omega,
    float* __restrict__ out)
{
    __shared__ float2 A[NH + (NH >> 4)];
    const int tid = threadIdx.x;
    const int bid = blockIdx.x;
    const int g   = bid & 63;               // (b,k) group
    const int c   = bid >> 6;
    const int b   = g >> 2, k = g & 3;
    const int ch  = b * 4 + c;
    const unsigned* pos = ws_u + (size_t)(ch * KMODES + k) * HALF;

    if (bid == 0 && tid < 64) {
        int bb = tid >> 2, kk = tid & 3;
        float s = 0.f;
        #pragma unroll
        for (int cc = 0; cc < 4; ++cc) s += ws_omega[(bb * 4 + cc) * 4 + kk];
        out[2097152 + tid] = 0.25f * s;
    }

    for (int j = tid; j < NH; j += NTHREADS) {
        v2f pj = unpack_h2(pos[j]);
        v2f ph = unpack_h2(pos[j ? (HALF - j) : (HALF - 1)]);
        float gjx = pj.x, gjy = (j == 0) ? -pj.y : pj.y;  // G[0] = conj(p[0])
        float ghx = ph.x, ghy = -ph.y;                     // conj
        float ex = 0.5f * (gjx + ghx), ey = 0.5f * (gjy + ghy);
        float dx = 0.5f * (gjx - ghx), dy = 0.5f * (gjy - ghy);
        float rev = (float)j * (1.0f / 16384.0f);
        float wr = __builtin_amdgcn_cosf(rev);
        float wi = __builtin_amdgcn_sinf(rev);    // e^{+2*pi*i*rev}
        float ox = dx * wr - dy * wi;
        float oy = dx * wi + dy * wr;
        A[pidx(j)] = make_float2(ex - oy, ey + ox);   // Z = E + i*O
    }
    __syncthreads();

    // 8192-pt inverse FFT: 4 radix-8 passes + 1 radix-2 stage; bit-reversed out.
    for (int t = 0; t < 4; ++t) {
        fft_pass8<true>(A, tid, t);
        __syncthreads();
    }
    fft_last2(A, tid);
    __syncthreads();

    // Keep n in [4096,12288): m in [2048,6144). x[2m]=Re z, x[2m+1]=Im z.
    float* outp = out + (size_t)(b * 4 + k) * 8192 * 4 + c;
    for (int m = 2048 + tid; m < 6144; m += NTHREADS) {
        float2 z = A[pidx((int)bitrev13((unsigned)m))];
        int t0 = 2 * m - 4096;
        outp[(size_t)t0 * 4]       = z.x * (1.0f / 8192.0f);
        outp[(size_t)(t0 + 1) * 4] = z.y * (1.0f / 8192.0f);
    }
}

extern "C" void kernel_launch(void* const* d_in, const int* in_sizes, int n_in,
                              void* d_out, int out_size, void* d_ws, size_t ws_size,
                              hipStream_t stream)
{
    (void)in_sizes; (void)n_in; (void)out_size; (void)ws_size;
    const float* x = (const float*)d_in[0];
    float* out = (float*)d_out;

    unsigned* ws_u     = (unsigned*)d_ws;  // 64 ch * 4 modes * 8192 u32 = 8 MB
    float*    ws_omega = (float*)((char*)d_ws + (size_t)64 * 4 * HALF * 4);

    vmd_forward_iter<<<64, NTHREADS, 0, stream>>>(x, ws_u, ws_omega);
    vmd_inverse<<<256, NTHREADS, 0, stream>>>(ws_u, ws_omega, out);
}

// Round 16
// 163.826 us; speedup vs baseline: 1.0893x; 1.0893x over previous
//
#include <hip/hip_runtime.h>

// VMD (Variational Mode Decomposition) for x: (16, 8192, 4) f32.
// B=16, C=4, T=8192, T2=16384, K=4, ALPHA=2000, TAU=0, 20 iterations.
// TAU=0 => lam == 0. Negative half stays 0 => iterate on 8192 positive bins.
//
// R16 = exact revert to R14 (best verified: 165.0us; forward 99.6us).
// R15's inline-asm v_fma_mix pinned registers and re-introduced scratch
// spill (WRITE 9.3->16.9MB, forward +16us) — intrinsics only, no asm.
// Structure: fwd = half-size real FFT (radix-8, padded LDS) + 20 issue-bound
// iterations (packed f32, f16 U, DPP reduce, 1 barrier/iter);
// inv = 256 blocks, same-XCD write-merge remap; omega fused into inverse.

#define HALF      8192
#define NH        8192        // half-size FFT length
#define NTHREADS  1024
#define KMODES    4
#define NITERS    20
#define ALPHA_F   2000.0f
#define SQH       0.70710678118654752440f

typedef __fp16 half2_t __attribute__((ext_vector_type(2)));
typedef float  v2f     __attribute__((ext_vector_type(2)));

__device__ __forceinline__ unsigned bitrev13(unsigned x) { return __brev(x) >> 19; }
__device__ __forceinline__ int pidx(int i) { return i + (i >> 4); }   // LDS pad

__device__ __forceinline__ unsigned pack_h2(float a, float b) {
    half2_t h = __builtin_amdgcn_cvt_pkrtz(a, b);   // v_cvt_pkrtz_f16_f32
    return __builtin_bit_cast(unsigned, h);
}
__device__ __forceinline__ v2f unpack_h2(unsigned u) {
    half2_t h = __builtin_bit_cast(half2_t, u);
    v2f r; r.x = (float)h.x; r.y = (float)h.y; return r;
}

template <int CTRL>
__device__ __forceinline__ float dpp_add_step(float v) {
    int r = __builtin_amdgcn_update_dpp(0, __float_as_int(v), CTRL, 0xf, 0xf, true);
    return v + __int_as_float(r);
}
// Full-wave (64-lane) sum; result valid in lane 63.
__device__ __forceinline__ float wave64_sum(float v) {
    v = dpp_add_step<0x111>(v);   // row_shr:1
    v = dpp_add_step<0x112>(v);   // row_shr:2
    v = dpp_add_step<0x114>(v);   // row_shr:4
    v = dpp_add_step<0x118>(v);   // row_shr:8
    v = dpp_add_step<0x142>(v);   // row_bcast:15
    v = dpp_add_step<0x143>(v);   // row_bcast:31 -> lane63 = wave sum
    return v;
}

__device__ __forceinline__ float2 cmul(float2 a, float wr, float wi) {
    return make_float2(a.x * wr - a.y * wi, a.x * wi + a.y * wr);
}
__device__ __forceinline__ float2 cadd(float2 a, float2 b) {
    return make_float2(a.x + b.x, a.y + b.y);
}
__device__ __forceinline__ float2 csub(float2 a, float2 b) {
    return make_float2(a.x - b.x, a.y - b.y);
}

// One radix-8 pass = three fused radix-2 DIF stages.
template <bool INV>
__device__ __forceinline__ void fft_pass8(float2* A, int tid, int t) {
    const int   log2Q = 10 - 3 * t;
    const int   Q     = 1 << log2Q;
    const float invL  = (float)(1 << (3 * t)) * (1.0f / 8192.0f);  // 1/(8Q)
    const int j    = tid & (Q - 1);
    const int base = ((tid >> log2Q) << (log2Q + 3)) + j;

    float2 x[8];
    #pragma unroll
    for (int m = 0; m < 8; ++m) x[m] = A[pidx(base + m * Q)];

    float rev = (float)j * invL;
    float w1r = __builtin_amdgcn_cosf(rev);
    float w1i = INV ?  __builtin_amdgcn_sinf(rev)
                    : -__builtin_amdgcn_sinf(rev);
    float w2r = w1r * w1r - w1i * w1i, w2i = 2.0f * w1r * w1i;
    float w4r = w2r * w2r - w2i * w2i, w4i = 2.0f * w2r * w2i;
    float wsr, wsi;
    if (INV) { wsr = SQH * (w1r - w1i); wsi = SQH * (w1r + w1i); }
    else     { wsr = SQH * (w1r + w1i); wsi = SQH * (w1i - w1r); }
    float w1tr = INV ? -w1i : w1i,  w1ti = INV ? w1r : -w1r;
    float wstr = INV ? -wsi : wsi,  wsti = INV ? wsr : -wsr;
    float w2tr = INV ? -w2i : w2i,  w2ti = INV ? w2r : -w2r;

    float2 y0 = cadd(x[0], x[4]), y1 = cadd(x[1], x[5]);
    float2 y2 = cadd(x[2], x[6]), y3 = cadd(x[3], x[7]);
    float2 y4 = cmul(csub(x[0], x[4]), w1r, w1i);
    float2 y5 = cmul(csub(x[1], x[5]), wsr, wsi);
    float2 y6 = cmul(csub(x[2], x[6]), w1tr, w1ti);
    float2 y7 = cmul(csub(x[3], x[7]), wstr, wsti);

    float2 z0 = cadd(y0, y2), z2 = cmul(csub(y0, y2), w2r, w2i);
    float2 z1 = cadd(y1, y3), z3 = cmul(csub(y1, y3), w2tr, w2ti);
    float2 z4 = cadd(y4, y6), z6 = cmul(csub(y4, y6), w2r, w2i);
    float2 z5 = cadd(y5, y7), z7 = cmul(csub(y5, y7), w2tr, w2ti);

    A[pidx(base + 0 * Q)] = cadd(z0, z1);
    A[pidx(base + 1 * Q)] = cmul(csub(z0, z1), w4r, w4i);
    A[pidx(base + 2 * Q)] = cadd(z2, z3);
    A[pidx(base + 3 * Q)] = cmul(csub(z2, z3), w4r, w4i);
    A[pidx(base + 4 * Q)] = cadd(z4, z5);
    A[pidx(base + 5 * Q)] = cmul(csub(z4, z5), w4r, w4i);
    A[pidx(base + 6 * Q)] = cadd(z6, z7);
    A[pidx(base + 7 * Q)] = cmul(csub(z6, z7), w4r, w4i);
}

// Final radix-2 stage (half=1): pairs (2t, 2t+1), twiddle = 1.
__device__ __forceinline__ void fft_last2(float2* A, int tid) {
    #pragma unroll
    for (int u = 0; u < 4; ++u) {
        int t  = tid + u * NTHREADS;
        int i0 = 2 * t, i1 = 2 * t + 1;
        float2 a = A[pidx(i0)], b = A[pidx(i1)];
        A[pidx(i0)] = make_float2(a.x + b.x, a.y + b.y);
        A[pidx(i1)] = make_float2(a.x - b.x, a.y - b.y);
    }
}

// time-domain mirror extension: f[i], i in [0,16384)
__device__ __forceinline__ int mirror_t(int i) {
    if (i < 4096)       return 4095 - i;
    else if (i < 12288) return i - 4096;
    else                return 20479 - i;
}

// ---------------------------------------------------------------------------
// Kernel 1: per-channel real-FFT (half-size, radix-8) + 20 VMD iterations.
// One block per channel (ch = b*4 + c), 1024 threads, 8 bins/thread.
// Writes u_hat packed-f16 (unsigned per bin).
// ---------------------------------------------------------------------------
__global__ __launch_bounds__(NTHREADS) void vmd_forward_iter(
    const float* __restrict__ x, unsigned* __restrict__ ws_u,
    float* __restrict__ ws_omega)
{
    __shared__ float2 A[NH + (NH >> 4)];   // padded, ~68 KB
    const int tid = threadIdx.x;
    const int ch  = blockIdx.x;          // b*4 + c
    const int b   = ch >> 2, c = ch & 3;
    const float* xb = x + (size_t)b * 8192 * 4 + c;   // x[b, t, c], stride 4

    // z[m] = f[2m] + i f[2m+1]
    for (int m = tid; m < NH; m += NTHREADS) {
        float re = xb[(size_t)mirror_t(2 * m) * 4];
        float im = xb[(size_t)mirror_t(2 * m + 1) * 4];
        A[pidx(m)] = make_float2(re, im);
    }
    __syncthreads();

    // 8192-pt forward FFT: 4 radix-8 passes + 1 radix-2 stage; bit-reversed out.
    for (int t = 0; t < 4; ++t) {
        fft_pass8<false>(A, tid, t);
        __syncthreads();
    }
    fft_last2(A, tid);
    __syncthreads();

    // Untangle: F[j] = E[j] + w*O[j], w = e^{-2*pi*i*j/16384}, j=0..8191.
    v2f R[8];
    #pragma unroll
    for (int u = 0; u < 8; ++u) {
        int j  = tid + u * NTHREADS;
        float2 z1 = A[pidx((int)bitrev13((unsigned)j))];
        float2 z2 = A[pidx((int)bitrev13((unsigned)((NH - j) & (NH - 1))))];
        float ex = 0.5f * (z1.x + z2.x);
        float ey = 0.5f * (z1.y - z2.y);
        float dx = 0.5f * (z1.x - z2.x);
        float dy = 0.5f * (z1.y + z2.y);
        // O = (dy, -dx)
        float rev = (float)j * (1.0f / 16384.0f);
        float wr = __builtin_amdgcn_cosf(rev);
        float wi = -__builtin_amdgcn_sinf(rev);
        R[u].x = ex + wr * dy + wi * dx;
        R[u].y = ey + wi * dy - wr * dx;
    }
    __syncthreads();   // LDS now reusable as reduction scratch

    unsigned Up[KMODES][8];    // U_k packed as (f16 re, f16 im)
    #pragma unroll
    for (int u = 0; u < 8; ++u)
        #pragma unroll
        for (int k = 0; k < KMODES; ++k) Up[k][u] = 0u;

    const float f0 = (float)tid * (1.0f / 16384.0f);    // fr[u] = f0 + u/16
    float omg[KMODES] = {0.0f, 0.125f, 0.25f, 0.375f};  // 0.5*k/K

    float* red = (float*)A;   // two 136-float slabs (double-buffered by parity)
    const int lane = tid & 63, wid = tid >> 6;

    for (int it = 0; it < NITERS; ++it) {
        v2f nd[KMODES];       // (num, den) packed per mode
        #pragma unroll
        for (int k = 0; k < KMODES; ++k) { nd[k].x = 0.f; nd[k].y = 0.f; }
        #pragma unroll
        for (int u = 0; u < 8; ++u) {
            const float fru = f0 + (float)u * 0.0625f;
            v2f fv; fv.x = fru; fv.y = 1.0f;
            #pragma unroll
            for (int k = 0; k < KMODES; ++k) {
                float d   = fru - omg[k];
                float dnm = fmaf(ALPHA_F * d, d, 1.0f);
                float rcp = __builtin_amdgcn_rcpf(dnm);
                v2f uo  = unpack_h2(Up[k][u]);
                v2f nm  = R[u] + uo;          // v_pk_add_f32
                v2f un  = nm * rcp;           // v_pk_mul_f32 (splat)
                R[u]    = nm - un;            // v_pk_add_f32
                Up[k][u] = pack_h2(un.x, un.y);
                float p = fmaf(un.x, un.x, un.y * un.y);
                nd[k]   = fv * p + nd[k];     // v_pk_fma_f32
            }
        }
        // Stage 1: DPP wave sums, lane63 writes 8 partials for this wave.
        float num[KMODES], den[KMODES];
        #pragma unroll
        for (int m = 0; m < KMODES; ++m) {
            num[m] = wave64_sum(nd[m].x);
            den[m] = wave64_sum(nd[m].y);
        }
        float* redb = red + (it & 1) * 136;
        if (lane == 63) {
            float4* r4 = (float4*)&redb[wid * 8];
            r4[0] = make_float4(num[0], num[1], num[2], num[3]);
            r4[1] = make_float4(den[0], den[1], den[2], den[3]);
        }
        __syncthreads();   // the ONLY barrier this iteration
        // Every wave redundantly folds the 16x8 partials.
        float v = redb[lane] + redb[lane + 64];
        v += __int_as_float(__builtin_amdgcn_ds_swizzle(__float_as_int(v), 0x201F)); // xor 8
        v += __int_as_float(__builtin_amdgcn_ds_swizzle(__float_as_int(v), 0x401F)); // xor 16
        v += __int_as_float(__builtin_amdgcn_ds_bpermute((lane ^ 32) << 2,
                                                         __float_as_int(v)));
        #pragma unroll
        for (int m = 0; m < KMODES; ++m) {
            float nm_ = __int_as_float(__builtin_amdgcn_readlane(__float_as_int(v), m));
            float dn_ = __int_as_float(__builtin_amdgcn_readlane(__float_as_int(v), m + 4));
            omg[m] = nm_ * __builtin_amdgcn_rcpf(dn_);
        }
    }

    // Write final positive-half u_hat (packed f16) and omega.
    #pragma unroll
    for (int k = 0; k < KMODES; ++k) {
        unsigned* dst = ws_u + (size_t)(ch * KMODES + k) * HALF;
        #pragma unroll
        for (int u = 0; u < 8; ++u)
            dst[tid + u * NTHREADS] = Up[k][u];
    }
    if (tid < KMODES) ws_omega[ch * KMODES + tid] = omg[tid];
}

// ---------------------------------------------------------------------------
// Kernel 2: per (channel,mode) half-size real iFFT -> out[b,k,t,c] scatter.
// Block remap for WRITE merging: g = bid & 63 -> (b = g>>2, k = g&3),
// c = bid >> 6, ch = b*4+c (same-XCD partial-write merging, R13).
// Block 0 also computes omega_b[b,k] = mean_c omega[b,c,k].
// Spectrum (verified R1): G[0]=conj(p[0]); G[j]=p[j]; G[8192]=conj(p[8191]);
// G[16384-j]=conj(p[j]).  Half-size: E=(G[j]+G[j+8192])/2,
// D=(G[j]-G[j+8192])/2, O=D*e^{+2pi i j/16384}, Z=E+iO, z=iFFT_8192(Z),
// x[2m]=Re z[m], x[2m+1]=Im z[m]; keep m in [2048,6144).
// ---------------------------------------------------------------------------
__global__ __launch_bounds__(NTHREADS) void vmd_inverse(
    const unsigned* __restrict__ ws_u, const float* __restrict__ ws_omega,
    float* __restrict__ out)
{
    __shared__ float2 A[NH + (NH >> 4)];
    const int tid = threadIdx.x;
    const int bid = blockIdx.x;
    const int g   = bid & 63;               // (b,k) group
    const int c   = bid >> 6;
    const int b   = g >> 2, k = g & 3;
    const int ch  = b * 4 + c;
    const unsigned* pos = ws_u + (size_t)(ch * KMODES + k) * HALF;

    if (bid == 0 && tid < 64) {
        int bb = tid >> 2, kk = tid & 3;
        float s = 0.f;
        #pragma unroll
        for (int cc = 0; cc < 4; ++cc) s += ws_omega[(bb * 4 + cc) * 4 + kk];
        out[2097152 + tid] = 0.25f * s;
    }

    for (int j = tid; j < NH; j += NTHREADS) {
        v2f pj = unpack_h2(pos[j]);
        v2f ph = unpack_h2(pos[j ? (HALF - j) : (HALF - 1)]);
        float gjx = pj.x, gjy = (j == 0) ? -pj.y : pj.y;  // G[0] = conj(p[0])
        float ghx = ph.x, ghy = -ph.y;                     // conj
        float ex = 0.5f * (gjx + ghx), ey = 0.5f * (gjy + ghy);
        float dx = 0.5f * (gjx - ghx), dy = 0.5f * (gjy - ghy);
        float rev = (float)j * (1.0f / 16384.0f);
        float wr = __builtin_amdgcn_cosf(rev);
        float wi = __builtin_amdgcn_sinf(rev);    // e^{+2*pi*i*rev}
        float ox = dx * wr - dy * wi;
        float oy = dx * wi + dy * wr;
        A[pidx(j)] = make_float2(ex - oy, ey + ox);   // Z = E + i*O
    }
    __syncthreads();

    // 8192-pt inverse FFT: 4 radix-8 passes + 1 radix-2 stage; bit-reversed out.
    for (int t = 0; t < 4; ++t) {
        fft_pass8<true>(A, tid, t);
        __syncthreads();
    }
    fft_last2(A, tid);
    __syncthreads();

    // Keep n in [4096,12288): m in [2048,6144). x[2m]=Re z, x[2m+1]=Im z.
    float* outp = out + (size_t)(b * 4 + k) * 8192 * 4 + c;
    for (int m = 2048 + tid; m < 6144; m += NTHREADS) {
        float2 z = A[pidx((int)bitrev13((unsigned)m))];
        int t0 = 2 * m - 4096;
        outp[(size_t)t0 * 4]       = z.x * (1.0f / 8192.0f);
        outp[(size_t)(t0 + 1) * 4] = z.y * (1.0f / 8192.0f);
    }
}

extern "C" void kernel_launch(void* const* d_in, const int* in_sizes, int n_in,
                              void* d_out, int out_size, void* d_ws, size_t ws_size,
                              hipStream_t stream)
{
    (void)in_sizes; (void)n_in; (void)out_size; (void)ws_size;
    const float* x = (const float*)d_in[0];
    float* out = (float*)d_out;

    unsigned* ws_u     = (unsigned*)d_ws;  // 64 ch * 4 modes * 8192 u32 = 8 MB
    float*    ws_omega = (float*)((char*)d_ws + (size_t)64 * 4 * HALF * 4);

    vmd_forward_iter<<<64, NTHREADS, 0, stream>>>(x, ws_u, ws_omega);
    vmd_inverse<<<256, NTHREADS, 0, stream>>>(ws_u, ws_omega, out);
}